// Round 7
// baseline (10555.213 us; speedup 1.0000x reference)
//
#include <hip/hip_runtime.h>
#include <math.h>

#define LL  32
#define HH  128
#define NQ  8     // k-slice groups
#define NS  4     // samples per block
#define KPT 16    // HH/NQ k-elements per thread

// Block = 4 samples, 1024 threads: tid = q*128 + j, q in 0..7.
// Round-1/2 lesson: 160 weight floats/thread do NOT fit (compiler allocated
// 120-124 VGPRs and cycled weights through scratch/L2 every site -> ~2.5x
// VALU-instruction inflation, 4.8 ms). With 1024 threads each thread holds
// only KPT=16 k-elements of the five 128x128 matrices = 80 VGPRs, which fits
// the 128-VGPR budget of 4 waves/SIMD -> weights truly register-resident.
// Phases per site: [depth-0 partials] A [reduce->h0] B [depth-1 partials
// (WH1,WV1 on old h1 carries, WS1 on fresh h0)] C [reduce->h1 + head] D.
// One shared partial buffer P is written in phase-0, consumed in reduce-0,
// overwritten in phase-1, consumed in reduce-1 (barriers make this safe).
// Carries live in LDS in lattice order; carry[s][c][d] is overwritten in
// place as the scan passes column c (old value = vertical carry from the
// previous row; new value = this row's h, read back as horizontal carry).
__global__ __launch_bounds__(1024, 4)
void rnn2d_kernel(const int* __restrict__ x,
                  const float* __restrict__ WH,
                  const float* __restrict__ WV,
                  const float* __restrict__ WS0,
                  const float* __restrict__ WS1,
                  const float* __restrict__ Wout,
                  const float* __restrict__ bout,
                  float* __restrict__ out)
{
    __shared__ float carry[NS][LL][2][HH];   // 128 KB
    __shared__ float P[NS][NQ][HH];          // 16 KB, reused by both phases
    __shared__ float red[NS][2];
    __shared__ int   xrow[NS][LL];
    __shared__ int   xprev[NS][LL];

    const int tid = threadIdx.x;    // 0..1023
    const int j   = tid & (HH - 1);
    const int q   = tid >> 7;       // 0..7
    const int k0  = q * KPT;
    const int b4  = blockIdx.x * NS;

    // ---- weight columns into registers (coalesced over j, one-time) ----
    float wh0[KPT], wv0[KPT], wh1[KPT], wv1[KPT], ws1r[KPT];
#pragma unroll
    for (int i = 0; i < KPT; ++i) {
        const int k = k0 + i;
        wh0[i]  = WH[k * HH + j];
        wv0[i]  = WV[k * HH + j];
        wh1[i]  = WH[(HH + k) * HH + j];
        wv1[i]  = WV[(HH + k) * HH + j];
        ws1r[i] = WS1[k * HH + j];
    }
#pragma unroll
    for (int i = 0; i < KPT; ++i)
        asm volatile("" : "+v"(wh0[i]), "+v"(wv0[i]), "+v"(wh1[i]),
                          "+v"(wv1[i]), "+v"(ws1r[i]));

    float s0a = WS0[0 * HH + j];   // xH == 0
    float s0b = WS0[1 * HH + j];   // xH == 1
    float s0c = WS0[2 * HH + j];   // xV == 0
    float s0d = WS0[3 * HH + j];   // xV == 1
    float wo  = Wout[j];
    float bo  = bout[0];
    asm volatile("" : "+v"(s0a), "+v"(s0b), "+v"(s0c), "+v"(s0d), "+v"(wo), "+v"(bo));

    for (int i = tid; i < NS * LL * 2 * HH; i += 1024) ((float*)carry)[i] = 0.0f;

    float total = 0.0f;   // per-sample sum, held by the (q<4, j==0) threads

#pragma unroll 1
    for (int r = 0; r < LL; ++r) {
        if (tid < NS * LL) {
            xrow[tid >> 5][tid & 31] = x[(b4 + (tid >> 5)) * (LL * LL) + r * LL + (tid & 31)];
        } else if (tid < 2 * NS * LL) {
            const int t2 = tid - NS * LL;
            xprev[t2 >> 5][t2 & 31] =
                (r > 0) ? x[(b4 + (t2 >> 5)) * (LL * LL) + (r - 1) * LL + (t2 & 31)] : 0;
        }
        __syncthreads();   // staging visible (also covers zero-init on r==0)

        const int dir = (r & 1) ? -1 : 1;
#pragma unroll 1
        for (int p = 0; p < LL; ++p) {
            const int c   = (dir == 1) ? p : (LL - 1 - p);
            const int cp  = c - dir;                 // valid only for p>0
            const int cps = (p == 0) ? c : cp;       // safe index for address formation

            // ---- phase 0: depth-0 partials (WH0 @ hH0, WV0 @ hV0) ----
#pragma unroll
            for (int smp = 0; smp < NS; ++smp) {
                const float* cH = &carry[smp][cps][0][0];
                const float* cV = &carry[smp][c][0][0];
                float a0 = 0.f, a1 = 0.f, a2 = 0.f, a3 = 0.f;
#pragma unroll
                for (int i = 0; i < KPT; i += 4) {
                    const float4 v4 = *(const float4*)(cV + k0 + i);   // uniform -> broadcast
                    float4 h4;
                    if (p > 0) h4 = *(const float4*)(cH + k0 + i);
                    else       h4 = make_float4(0.f, 0.f, 0.f, 0.f);
                    a0 = fmaf(h4.x, wh0[i + 0], a0);
                    a1 = fmaf(h4.y, wh0[i + 1], a1);
                    a2 = fmaf(h4.z, wh0[i + 2], a2);
                    a3 = fmaf(h4.w, wh0[i + 3], a3);
                    a0 = fmaf(v4.x, wv0[i + 0], a0);
                    a1 = fmaf(v4.y, wv0[i + 1], a1);
                    a2 = fmaf(v4.z, wv0[i + 2], a2);
                    a3 = fmaf(v4.w, wv0[i + 3], a3);
                }
                P[smp][q][j] = (a0 + a1) + (a2 + a3);
            }
            __syncthreads();   // A: depth-0 partials visible

            // ---- reduce 0: threads (q<4, j) finalize h0 of sample q ----
            if (q < 4) {
                float s = ((P[q][0][j] + P[q][1][j]) + (P[q][2][j] + P[q][3][j]))
                        + ((P[q][4][j] + P[q][5][j]) + (P[q][6][j] + P[q][7][j]));
                if (p > 0) s += (xrow[q][cp] == 0) ? s0a : s0b;
                if (r > 0) s += (xprev[q][c] == 0) ? s0c : s0d;
                s = (s > 0.f) ? s : expm1f(s);                 // elu
                carry[q][c][0][j] = s;                         // h0 (old value already consumed)
            }
            __syncthreads();   // B: h0 broadcast; P free for reuse

            // ---- phase 1: depth-1 partials (WH1,WV1 on old h1 carries; WS1 on h0) ----
#pragma unroll
            for (int smp = 0; smp < NS; ++smp) {
                const float* cH1 = &carry[smp][cps][1][0];
                const float* cV1 = &carry[smp][c][1][0];       // old h1 (not yet overwritten)
                const float* h0p = &carry[smp][c][0][0];       // fresh h0
                float a0 = 0.f, a1 = 0.f, a2 = 0.f, a3 = 0.f;
#pragma unroll
                for (int i = 0; i < KPT; i += 4) {
                    const float4 v4 = *(const float4*)(cV1 + k0 + i);
                    const float4 s4 = *(const float4*)(h0p + k0 + i);
                    float4 h4;
                    if (p > 0) h4 = *(const float4*)(cH1 + k0 + i);
                    else       h4 = make_float4(0.f, 0.f, 0.f, 0.f);
                    a0 = fmaf(h4.x, wh1[i + 0], a0);
                    a1 = fmaf(h4.y, wh1[i + 1], a1);
                    a2 = fmaf(h4.z, wh1[i + 2], a2);
                    a3 = fmaf(h4.w, wh1[i + 3], a3);
                    a0 = fmaf(v4.x, wv1[i + 0], a0);
                    a1 = fmaf(v4.y, wv1[i + 1], a1);
                    a2 = fmaf(v4.z, wv1[i + 2], a2);
                    a3 = fmaf(v4.w, wv1[i + 3], a3);
                    a0 = fmaf(s4.x, ws1r[i + 0], a0);
                    a1 = fmaf(s4.y, ws1r[i + 1], a1);
                    a2 = fmaf(s4.z, ws1r[i + 2], a2);
                    a3 = fmaf(s4.w, ws1r[i + 3], a3);
                }
                P[smp][q][j] = (a0 + a1) + (a2 + a3);
            }
            __syncthreads();   // C: depth-1 partials visible

            // ---- reduce 1: h1, output head ----
            int xc = 0;
            if (q < 4) {
                float t = ((P[q][0][j] + P[q][1][j]) + (P[q][2][j] + P[q][3][j]))
                        + ((P[q][4][j] + P[q][5][j]) + (P[q][6][j] + P[q][7][j]));
                t = (t > 0.f) ? t : expm1f(t);                 // elu -> h1
                carry[q][c][1][j] = t;
                float g = t * wo;
#pragma unroll
                for (int off = 32; off > 0; off >>= 1)
                    g += __shfl_down(g, off, 64);
                if ((tid & 63) == 0) red[q][(tid >> 6) & 1] = g;   // 2 waves per sample
                xc = xrow[q][c];   // pre-read: avoids race with next-row staging
            }
            __syncthreads();   // D: h1 + head partials visible

            if (q < 4 && j == 0) {
                const float t  = red[q][0] + red[q][1] + bo;
                const float sp = fmaxf(t, 0.f) + log1pf(expf(-fabsf(t)));   // softplus
                total += 0.5f * (((xc == 1) ? t : 0.f) - sp);               // 0.5*log_softmax pick
            }
        }
    }
    if (q < 4 && j == 0) out[b4 + q] = total;
}

extern "C" void kernel_launch(void* const* d_in, const int* in_sizes, int n_in,
                              void* d_out, int out_size, void* d_ws, size_t ws_size,
                              hipStream_t stream) {
    rnn2d_kernel<<<dim3(1024 / NS), dim3(1024), 0, stream>>>(
        (const int*)  d_in[0],   // x      (B,L,L) int32
        (const float*)d_in[1],   // WH     (2,128,128)
        (const float*)d_in[2],   // WV     (2,128,128)
        (const float*)d_in[3],   // WS0    (4,128)
        (const float*)d_in[4],   // WS1    (128,128)
        (const float*)d_in[5],   // Wout   (128,1)
        (const float*)d_in[6],   // bout   (1,)
        (float*)d_out);          // (B,) fp32
}

// Round 8
// 4510.320 us; speedup vs baseline: 2.3402x; 2.3402x over previous
//
#include <hip/hip_runtime.h>
#include <math.h>

#define LL  32
#define HH  128
#define NQ  4     // k-slice groups
#define NS  4     // samples per block
#define KPT 32    // HH/NQ k-elements per thread

// Block = 4 samples, 512 threads: tid = q*128 + j.
// Evidence R1/R3/R7: the register allocator's occupancy heuristic (not the
// __launch_bounds__ minimum) sets the VGPR budget. R3 (512t, pins): VGPR=124,
// weights parked in AGPRs (no scratch, WRITE_SIZE=8) -> 4.5 ms. R7 (1024t):
// budget collapsed to 64 -> pinned weights spilled to scratch/HBM (295 GB
// writes) -> 10.5 ms. Fix: pin the waves/EU range with amdgpu_waves_per_eu(2,2)
// -> 256-VGPR budget, which fits 160 weight floats + ~60 working regs in true
// VGPRs. LDS ~145 KB forces 1 block/CU (8 waves = 2/EU) anyway, so max=2
// sacrifices nothing.
__global__ __launch_bounds__(512)
__attribute__((amdgpu_waves_per_eu(2, 2)))
void rnn2d_kernel(const int* __restrict__ x,
                  const float* __restrict__ WH,
                  const float* __restrict__ WV,
                  const float* __restrict__ WS0,
                  const float* __restrict__ WS1,
                  const float* __restrict__ Wout,
                  const float* __restrict__ bout,
                  float* __restrict__ out)
{
    __shared__ float carry[NS][LL][2][HH];   // 128 KB
    __shared__ float Pa[NS][NQ][HH];         // 8 KB: depth-0 partials, reused for WS1 partials
    __shared__ float Pb[NS][NQ][HH];         // 8 KB: depth-1 H/V partials
    __shared__ float zbuf[2][HH];            // zeros, stands in for carryH at p==0
    __shared__ float red[NS][2];
    __shared__ int   xrow[NS][LL];
    __shared__ int   xprev[NS][LL];

    const int tid = threadIdx.x;
    const int j   = tid & (HH - 1);
    const int q   = tid >> 7;       // 0..3
    const int k0  = q * KPT;
    const int b4  = blockIdx.x * NS;

    // ---- weight columns into registers (coalesced over j, one-time) ----
    float wh0[KPT], wv0[KPT], wh1[KPT], wv1[KPT], ws1r[KPT];
#pragma unroll
    for (int i = 0; i < KPT; ++i) {
        const int k = k0 + i;
        wh0[i]  = WH[k * HH + j];
        wv0[i]  = WV[k * HH + j];
        wh1[i]  = WH[(HH + k) * HH + j];
        wv1[i]  = WV[(HH + k) * HH + j];
        ws1r[i] = WS1[k * HH + j];
    }
    // Pin as opaque register values: prevents rematerialization of the loads.
#pragma unroll
    for (int i = 0; i < KPT; ++i)
        asm volatile("" : "+v"(wh0[i]), "+v"(wv0[i]), "+v"(wh1[i]),
                          "+v"(wv1[i]), "+v"(ws1r[i]));

    const float s0a = WS0[0 * HH + j];   // xH == 0
    const float s0b = WS0[1 * HH + j];   // xH == 1
    const float s0c = WS0[2 * HH + j];   // xV == 0
    const float s0d = WS0[3 * HH + j];   // xV == 1
    const float wo  = Wout[j];
    const float bo  = bout[0];

    for (int i = tid; i < NS * LL * 2 * HH; i += 512) ((float*)carry)[i] = 0.0f;
    if (tid < 2 * HH) ((float*)zbuf)[tid] = 0.0f;

    float total = 0.0f;   // sample-q sum, held by the j==0 thread of group q

#pragma unroll 1
    for (int r = 0; r < LL; ++r) {
        if (tid < NS * LL) {
            xrow[tid >> 5][tid & 31] = x[(b4 + (tid >> 5)) * (LL * LL) + r * LL + (tid & 31)];
        } else if (tid < 2 * NS * LL) {
            const int t2 = tid - NS * LL;
            xprev[t2 >> 5][t2 & 31] =
                (r > 0) ? x[(b4 + (t2 >> 5)) * (LL * LL) + (r - 1) * LL + (t2 & 31)] : 0;
        }
        __syncthreads();   // staging visible (also covers r==0 zero-init)

        const int dir = (r & 1) ? -1 : 1;
#pragma unroll 1
        for (int p = 0; p < LL; ++p) {
            const int c  = (dir == 1) ? p : (LL - 1 - p);
            const int cp = c - dir;

            // ---- phase 0: depth-0 H/V + depth-1 H/V partials (all carries old) ----
#pragma unroll
            for (int smp = 0; smp < NS; ++smp) {
                const float* cH = (p == 0) ? &zbuf[0][0] : &carry[smp][cp][0][0];
                const float* cV = &carry[smp][c][0][0];
                float a0 = 0.f, a1 = 0.f, a2 = 0.f, a3 = 0.f;   // depth 0
                float e0 = 0.f, e1 = 0.f, e2 = 0.f, e3 = 0.f;   // depth 1 (H/V part)
#pragma unroll
                for (int i = 0; i < KPT; i += 4) {
                    const float4 h0 = *(const float4*)(cH + k0 + i);        // uniform -> broadcast
                    const float4 v0 = *(const float4*)(cV + k0 + i);
                    const float4 h1 = *(const float4*)(cH + HH + k0 + i);
                    const float4 v1 = *(const float4*)(cV + HH + k0 + i);
                    a0 = fmaf(h0.x, wh0[i + 0], a0);
                    a1 = fmaf(h0.y, wh0[i + 1], a1);
                    a2 = fmaf(h0.z, wh0[i + 2], a2);
                    a3 = fmaf(h0.w, wh0[i + 3], a3);
                    a0 = fmaf(v0.x, wv0[i + 0], a0);
                    a1 = fmaf(v0.y, wv0[i + 1], a1);
                    a2 = fmaf(v0.z, wv0[i + 2], a2);
                    a3 = fmaf(v0.w, wv0[i + 3], a3);
                    e0 = fmaf(h1.x, wh1[i + 0], e0);
                    e1 = fmaf(h1.y, wh1[i + 1], e1);
                    e2 = fmaf(h1.z, wh1[i + 2], e2);
                    e3 = fmaf(h1.w, wh1[i + 3], e3);
                    e0 = fmaf(v1.x, wv1[i + 0], e0);
                    e1 = fmaf(v1.y, wv1[i + 1], e1);
                    e2 = fmaf(v1.z, wv1[i + 2], e2);
                    e3 = fmaf(v1.w, wv1[i + 3], e3);
                }
                Pa[smp][q][j] = (a0 + a1) + (a2 + a3);
                Pb[smp][q][j] = (e0 + e1) + (e2 + e3);
            }
            __syncthreads();   // A: partials visible

            // ---- reduce 0: thread (q,j) finalizes h0 of sample q ----
            {
                float s = (Pa[q][0][j] + Pa[q][1][j]) + (Pa[q][2][j] + Pa[q][3][j]);
                if (p > 0) s += (xrow[q][cp] == 0) ? s0a : s0b;
                if (r > 0) s += (xprev[q][c] == 0) ? s0c : s0d;
                s = (s > 0.f) ? s : expm1f(s);                 // elu
                carry[q][c][0][j] = s;                         // h0 (old cV0 already consumed)
            }
            __syncthreads();   // B: h0 broadcast

            // ---- phase 1: WS1 @ h0 partials ----
#pragma unroll
            for (int smp = 0; smp < NS; ++smp) {
                const float* h0p = &carry[smp][c][0][0];
                float a0 = 0.f, a1 = 0.f, a2 = 0.f, a3 = 0.f;
#pragma unroll
                for (int i = 0; i < KPT; i += 4) {
                    const float4 s4 = *(const float4*)(h0p + k0 + i);
                    a0 = fmaf(s4.x, ws1r[i + 0], a0);
                    a1 = fmaf(s4.y, ws1r[i + 1], a1);
                    a2 = fmaf(s4.z, ws1r[i + 2], a2);
                    a3 = fmaf(s4.w, ws1r[i + 3], a3);
                }
                Pa[smp][q][j] = (a0 + a1) + (a2 + a3);   // reuse Pa (consumed at bar A..B)
            }
            __syncthreads();   // C: WS1 partials visible

            // ---- reduce 1: h1, output head ----
            int xc = 0;
            {
                float t = (Pa[q][0][j] + Pa[q][1][j]) + (Pa[q][2][j] + Pa[q][3][j])
                        + (Pb[q][0][j] + Pb[q][1][j]) + (Pb[q][2][j] + Pb[q][3][j]);
                t = (t > 0.f) ? t : expm1f(t);                 // elu -> h1
                carry[q][c][1][j] = t;
                float g = t * wo;
#pragma unroll
                for (int off = 32; off > 0; off >>= 1)
                    g += __shfl_down(g, off, 64);
                if ((j & 63) == 0) red[q][j >> 6] = g;         // two waves per sample
                xc = xrow[q][c];   // pre-read: avoids race with next-row staging after bar D
            }
            __syncthreads();   // D: h1 + head partials visible

            if (j == 0) {
                const float t  = red[q][0] + red[q][1] + bo;
                const float sp = fmaxf(t, 0.f) + log1pf(expf(-fabsf(t)));   // softplus
                total += 0.5f * (((xc == 1) ? t : 0.f) - sp);               // 0.5*log_softmax pick
            }
        }
    }
    if (j == 0) out[b4 + q] = total;
}

extern "C" void kernel_launch(void* const* d_in, const int* in_sizes, int n_in,
                              void* d_out, int out_size, void* d_ws, size_t ws_size,
                              hipStream_t stream) {
    rnn2d_kernel<<<dim3(1024 / NS), dim3(512), 0, stream>>>(
        (const int*)  d_in[0],   // x      (B,L,L) int32
        (const float*)d_in[1],   // WH     (2,128,128)
        (const float*)d_in[2],   // WV     (2,128,128)
        (const float*)d_in[3],   // WS0    (4,128)
        (const float*)d_in[4],   // WS1    (128,128)
        (const float*)d_in[5],   // Wout   (128,1)
        (const float*)d_in[6],   // bout   (1,)
        (float*)d_out);          // (B,) fp32
}